// Round 1
// baseline (309.180 us; speedup 1.0000x reference)
//
#include <hip/hip_runtime.h>
#include <math.h>

#define NTOK 4096
#define CDIM 256
#define NH   8
#define HD   32
#define SCALE 0.17677669529663687f  // 32^-0.5

// ---------------- fused QKV projection GEMM ----------------
// output cols [0,256):   q = (qkv+q_pos) @ Wq
//             [256,512): k = qkv @ Wkv[:, 0:256]
//             [512,768): v = qkv @ Wkv[:, 256:512]
// dst: ws laid out as q[4096][256] | k[4096][256] | v[4096][256] | feat[4096][256]
__global__ __launch_bounds__(256) void proj_qkv_kernel(
    const float* __restrict__ qkv, const float* __restrict__ q_pos,
    const float* __restrict__ Wq, const float* __restrict__ Wkv,
    float* __restrict__ ws)
{
  __shared__ float As[128][33];
  __shared__ float Bs[32][128];
  const int bx   = blockIdx.x;        // 0..5 -> global col tile
  const int n0   = blockIdx.y * 128;
  const int col0 = bx * 128;
  const int tid  = threadIdx.x;
  const int tm = tid >> 4, tn = tid & 15;
  const bool useSum = (bx < 2);       // q region uses qkv + q_pos
  const float* W; int ldw, wc0;
  if (useSum) { W = Wq;  ldw = 256; wc0 = col0; }
  else        { W = Wkv; ldw = 512; wc0 = col0 - 256; }
  float* dst = ws + (size_t)(bx >> 1) * (NTOK * CDIM);
  const int dcol = (bx & 1) * 128;

  float acc[8][8];
  #pragma unroll
  for (int i = 0; i < 8; ++i)
    #pragma unroll
    for (int j = 0; j < 8; ++j) acc[i][j] = 0.f;

  for (int kt = 0; kt < CDIM; kt += 32) {
    __syncthreads();
    // stage A tile 128x32 (1024 float4 slots)
    for (int s4 = tid; s4 < 1024; s4 += 256) {
      int r = s4 >> 3, c4 = s4 & 7;
      const float* src = qkv + (size_t)(n0 + r) * CDIM + kt + c4 * 4;
      float4 a = *(const float4*)src;
      if (useSum) {
        float4 b = *(const float4*)(q_pos + (size_t)(n0 + r) * CDIM + kt + c4 * 4);
        a.x += b.x; a.y += b.y; a.z += b.z; a.w += b.w;
      }
      int cc = c4 * 4;
      As[r][cc] = a.x; As[r][cc+1] = a.y; As[r][cc+2] = a.z; As[r][cc+3] = a.w;
    }
    // stage B tile 32x128 (1024 float4 slots)
    for (int s4 = tid; s4 < 1024; s4 += 256) {
      int r = s4 >> 5, c4 = s4 & 31;
      float4 wv = *(const float4*)(W + (size_t)(kt + r) * ldw + wc0 + c4 * 4);
      *(float4*)&Bs[r][c4 * 4] = wv;
    }
    __syncthreads();
    #pragma unroll 8
    for (int kk = 0; kk < 32; ++kk) {
      float a[8], b[8];
      #pragma unroll
      for (int i = 0; i < 8; ++i) a[i] = As[tm*8+i][kk];   // 4-addr broadcast
      float4 b0 = *(float4*)&Bs[kk][tn*8];
      float4 b1 = *(float4*)&Bs[kk][tn*8+4];
      b[0]=b0.x; b[1]=b0.y; b[2]=b0.z; b[3]=b0.w;
      b[4]=b1.x; b[5]=b1.y; b[6]=b1.z; b[7]=b1.w;
      #pragma unroll
      for (int i = 0; i < 8; ++i)
        #pragma unroll
        for (int j = 0; j < 8; ++j)
          acc[i][j] = fmaf(a[i], b[j], acc[i][j]);
    }
  }
  #pragma unroll
  for (int i = 0; i < 8; ++i) {
    float* dr = dst + (size_t)(n0 + tm*8 + i) * CDIM + dcol + tn*8;
    float4 o0 = {acc[i][0], acc[i][1], acc[i][2], acc[i][3]};
    float4 o1 = {acc[i][4], acc[i][5], acc[i][6], acc[i][7]};
    *(float4*)dr = o0;
    *(float4*)(dr + 4) = o1;
  }
}

// ---------------- output projection GEMM (+bias) ----------------
__global__ __launch_bounds__(256) void proj_out_kernel(
    const float* __restrict__ feat, const float* __restrict__ Wproj,
    const float* __restrict__ bproj, float* __restrict__ out)
{
  __shared__ float As[128][33];
  __shared__ float Bs[32][128];
  const int col0 = blockIdx.x * 128;  // 0 or 128
  const int n0   = blockIdx.y * 128;
  const int tid  = threadIdx.x;
  const int tm = tid >> 4, tn = tid & 15;

  float acc[8][8];
  #pragma unroll
  for (int i = 0; i < 8; ++i)
    #pragma unroll
    for (int j = 0; j < 8; ++j) acc[i][j] = 0.f;

  for (int kt = 0; kt < CDIM; kt += 32) {
    __syncthreads();
    for (int s4 = tid; s4 < 1024; s4 += 256) {
      int r = s4 >> 3, c4 = s4 & 7;
      float4 a = *(const float4*)(feat + (size_t)(n0 + r) * CDIM + kt + c4 * 4);
      int cc = c4 * 4;
      As[r][cc] = a.x; As[r][cc+1] = a.y; As[r][cc+2] = a.z; As[r][cc+3] = a.w;
    }
    for (int s4 = tid; s4 < 1024; s4 += 256) {
      int r = s4 >> 5, c4 = s4 & 31;
      float4 wv = *(const float4*)(Wproj + (size_t)(kt + r) * CDIM + col0 + c4 * 4);
      *(float4*)&Bs[r][c4 * 4] = wv;
    }
    __syncthreads();
    #pragma unroll 8
    for (int kk = 0; kk < 32; ++kk) {
      float a[8], b[8];
      #pragma unroll
      for (int i = 0; i < 8; ++i) a[i] = As[tm*8+i][kk];
      float4 b0 = *(float4*)&Bs[kk][tn*8];
      float4 b1 = *(float4*)&Bs[kk][tn*8+4];
      b[0]=b0.x; b[1]=b0.y; b[2]=b0.z; b[3]=b0.w;
      b[4]=b1.x; b[5]=b1.y; b[6]=b1.z; b[7]=b1.w;
      #pragma unroll
      for (int i = 0; i < 8; ++i)
        #pragma unroll
        for (int j = 0; j < 8; ++j)
          acc[i][j] = fmaf(a[i], b[j], acc[i][j]);
    }
  }
  float bj[8];
  #pragma unroll
  for (int j = 0; j < 8; ++j) bj[j] = bproj[col0 + tn*8 + j];
  #pragma unroll
  for (int i = 0; i < 8; ++i) {
    float* dr = out + (size_t)(n0 + tm*8 + i) * CDIM + col0 + tn*8;
    float4 o0 = {acc[i][0]+bj[0], acc[i][1]+bj[1], acc[i][2]+bj[2], acc[i][3]+bj[3]};
    float4 o1 = {acc[i][4]+bj[4], acc[i][5]+bj[5], acc[i][6]+bj[6], acc[i][7]+bj[7]};
    *(float4*)dr = o0;
    *(float4*)(dr + 4) = o1;
  }
}

// ---------------- segment-masked attention ----------------
// block = (64-query tile, head); 4 waves split keys of the tile's segment
// union 4 ways; per-lane online softmax; 4-way partial merge at the end.
__global__ __launch_bounds__(256) void attn_kernel(
    const float* __restrict__ qw, const float* __restrict__ kw,
    const float* __restrict__ vw, const int* __restrict__ cu,
    float* __restrict__ feat)
{
  __shared__ float kT[64][32];
  __shared__ float vT[64][32];
  __shared__ float pm[4][64];
  __shared__ float pl[4][64];
  __shared__ float pacc[4][64][33];
  const int h  = blockIdx.y;
  const int n0 = blockIdx.x * 64;
  const int tid = threadIdx.x;
  const int w = tid >> 6, l = tid & 63;
  int cs[9];
  #pragma unroll
  for (int i = 0; i < 9; ++i) cs[i] = cu[i];
  const int n = n0 + l;
  int sg = 0, sg0 = 0, sgL = 0;
  #pragma unroll
  for (int j = 1; j <= 8; ++j) {
    sg  += (cs[j] <= n);
    sg0 += (cs[j] <= n0);
    sgL += (cs[j] <= n0 + 63);
  }
  const int kbeg = cs[sg], kend = cs[sg + 1];   // this query's key range
  const int lo = cs[sg0], hi = cs[sgL + 1];     // block-uniform union range

  float ql[32];
  const float* qp = qw + (size_t)n * CDIM + h * HD;
  #pragma unroll
  for (int d4 = 0; d4 < 8; ++d4) {
    float4 t = *(const float4*)(qp + d4 * 4);
    ql[d4*4+0] = t.x; ql[d4*4+1] = t.y; ql[d4*4+2] = t.z; ql[d4*4+3] = t.w;
  }
  float m = -INFINITY, L = 0.f;
  float acc[32];
  #pragma unroll
  for (int d = 0; d < 32; ++d) acc[d] = 0.f;

  for (int tb = lo; tb < hi; tb += 64) {
    __syncthreads();
    // stage 64 keys+values for this head (512 float4 slots each)
    for (int s4 = tid; s4 < 512; s4 += 256) {
      int j = s4 >> 3, d4 = s4 & 7;
      int kg = tb + j; if (kg > NTOK - 1) kg = NTOK - 1;
      *(float4*)&kT[j][d4*4] = *(const float4*)(kw + (size_t)kg * CDIM + h * HD + d4 * 4);
      *(float4*)&vT[j][d4*4] = *(const float4*)(vw + (size_t)kg * CDIM + h * HD + d4 * 4);
    }
    __syncthreads();
    const int jbase = w * 16;
    for (int jj = 0; jj < 16; ++jj) {
      const int j = jbase + jj;
      const int kg = tb + j;
      float s = 0.f;
      #pragma unroll
      for (int d4 = 0; d4 < 8; ++d4) {
        float4 kv4 = *(float4*)&kT[j][d4*4];   // broadcast read
        s = fmaf(ql[d4*4+0], kv4.x, s);
        s = fmaf(ql[d4*4+1], kv4.y, s);
        s = fmaf(ql[d4*4+2], kv4.z, s);
        s = fmaf(ql[d4*4+3], kv4.w, s);
      }
      s *= SCALE;
      if (kg >= kbeg && kg < kend) {
        if (s > m) {             // rare after warm-up (~log(len) times)
          float c = __expf(m - s);
          m = s; L *= c;
          #pragma unroll
          for (int d = 0; d < 32; ++d) acc[d] *= c;
        }
        float p = __expf(s - m);
        L += p;
        #pragma unroll
        for (int d4 = 0; d4 < 8; ++d4) {
          float4 vv = *(float4*)&vT[j][d4*4];  // broadcast read
          acc[d4*4+0] = fmaf(p, vv.x, acc[d4*4+0]);
          acc[d4*4+1] = fmaf(p, vv.y, acc[d4*4+1]);
          acc[d4*4+2] = fmaf(p, vv.z, acc[d4*4+2]);
          acc[d4*4+3] = fmaf(p, vv.w, acc[d4*4+3]);
        }
      }
    }
  }
  // write per-wave partials and merge
  pm[w][l] = m; pl[w][l] = L;
  #pragma unroll
  for (int d = 0; d < 32; ++d) pacc[w][l][d] = acc[d];
  __syncthreads();
  if (w == 0) {
    float M = pm[0][l];
    M = fmaxf(M, pm[1][l]); M = fmaxf(M, pm[2][l]); M = fmaxf(M, pm[3][l]);
    float Lt = 0.f;
    float o[32];
    #pragma unroll
    for (int d = 0; d < 32; ++d) o[d] = 0.f;
    #pragma unroll
    for (int i = 0; i < 4; ++i) {
      float c = __expf(pm[i][l] - M);
      Lt = fmaf(pl[i][l], c, Lt);
      #pragma unroll
      for (int d = 0; d < 32; ++d) o[d] = fmaf(pacc[i][l][d], c, o[d]);
    }
    float inv = 1.f / Lt;
    float* fp = feat + (size_t)n * CDIM + h * HD;
    #pragma unroll
    for (int d4 = 0; d4 < 8; ++d4) {
      float4 t = { o[d4*4+0]*inv, o[d4*4+1]*inv, o[d4*4+2]*inv, o[d4*4+3]*inv };
      *(float4*)(fp + d4*4) = t;
    }
  }
}

extern "C" void kernel_launch(void* const* d_in, const int* in_sizes, int n_in,
                              void* d_out, int out_size, void* d_ws, size_t ws_size,
                              hipStream_t stream) {
  (void)in_sizes; (void)n_in; (void)out_size; (void)ws_size;
  const float* qkv   = (const float*)d_in[0];
  const float* q_pos = (const float*)d_in[1];
  const int*   cu    = (const int*)d_in[2];
  // d_in[3] = max_seqlen (unused)
  const float* Wq    = (const float*)d_in[4];
  const float* Wkv   = (const float*)d_in[5];
  const float* Wproj = (const float*)d_in[6];
  const float* bproj = (const float*)d_in[7];
  float* out = (float*)d_out;
  float* ws  = (float*)d_ws;
  float* qw   = ws;
  float* kw   = ws + (size_t)NTOK * CDIM;
  float* vw   = ws + 2 * (size_t)NTOK * CDIM;
  float* feat = ws + 3 * (size_t)NTOK * CDIM;

  proj_qkv_kernel<<<dim3(6, 32), 256, 0, stream>>>(qkv, q_pos, Wq, Wkv, ws);
  attn_kernel<<<dim3(NTOK / 64, NH), 256, 0, stream>>>(qw, kw, vw, cu, feat);
  proj_out_kernel<<<dim3(2, 32), 256, 0, stream>>>(feat, Wproj, bproj, out);
}

// Round 4
// 75.843 us; speedup vs baseline: 4.0766x; 4.0766x over previous
//
#include <hip/hip_runtime.h>
#include <hip/hip_bf16.h>
#include <math.h>

#define NTOK 4096
#define CDIM 256
#define NH   8
#define HD   32
#define SCALE 0.17677669529663687f  // 32^-0.5

typedef __attribute__((ext_vector_type(8))) short bf16x8;
typedef __attribute__((ext_vector_type(4))) short short4v;
typedef __attribute__((ext_vector_type(4))) float f32x4;

__device__ inline short f2b(float f) {
  union { __hip_bfloat16 h; short s; } u;
  u.h = __float2bfloat16(f);
  return u.s;
}
__device__ inline short4v pack4(f32x4 v) {
  short4v o; o[0] = f2b(v[0]); o[1] = f2b(v[1]); o[2] = f2b(v[2]); o[3] = f2b(v[3]);
  return o;
}

// ---------------- prep: bf16 conversions + weight transposes ----------------
__global__ __launch_bounds__(256) void prep_kernel(
    const float* __restrict__ qkv, const float* __restrict__ qpos,
    const float* __restrict__ Wq, const float* __restrict__ Wkv,
    const float* __restrict__ Wp,
    short* __restrict__ Xq, short* __restrict__ X,
    short* __restrict__ WT, short* __restrict__ WpT)
{
  const int b = blockIdx.x, t = threadIdx.x;
  if (b < 1024) {
    const int i4 = (b * 256 + t) * 4;
    float4 a = *(const float4*)(qkv + i4);
    float4 p = *(const float4*)(qpos + i4);
    short4v xo, qo;
    xo[0] = f2b(a.x); xo[1] = f2b(a.y); xo[2] = f2b(a.z); xo[3] = f2b(a.w);
    qo[0] = f2b(a.x + p.x); qo[1] = f2b(a.y + p.y); qo[2] = f2b(a.z + p.z); qo[3] = f2b(a.w + p.w);
    *(short4v*)(X + i4)  = xo;
    *(short4v*)(Xq + i4) = qo;
  } else {
    const int gid = (b - 1024) * 256 + t;   // 0..65535
    const int c  = gid & 1023;              // output row (transposed col)
    const int k4 = (gid >> 10) * 4;         // 0..252
    short4v o;
    if (c < 768) {
      #pragma unroll
      for (int j = 0; j < 4; ++j) {
        int k = k4 + j;
        float v = (c < 256) ? Wq[(size_t)k * 256 + c] * SCALE
                            : Wkv[(size_t)k * 512 + (c - 256)];
        o[j] = f2b(v);
      }
      *(short4v*)(WT + (size_t)c * 256 + k4) = o;
    } else {
      const int cc = c - 768;
      #pragma unroll
      for (int j = 0; j < 4; ++j) o[j] = f2b(Wp[(size_t)(k4 + j) * 256 + cc]);
      *(short4v*)(WpT + (size_t)cc * 256 + k4) = o;
    }
  }
}

// ---------------- fused QKV projection (MFMA) ----------------
__global__ __launch_bounds__(256) void gemm_qkv(
    const short* __restrict__ Xq, const short* __restrict__ X,
    const short* __restrict__ WT,
    short* __restrict__ qb, short* __restrict__ kb, short* __restrict__ vTb)
{
  __shared__ short Al[128][40];
  __shared__ short Wl[128][40];
  const int bx = blockIdx.x;
  const int n0 = blockIdx.y * 128;
  const int c0 = bx * 128;                  // row range in WT
  const int tid = threadIdx.x;
  const int w = tid >> 6, l = tid & 63, lg = l >> 4, lr = l & 15;
  const int cq = w >> 1, nq = w & 1;
  const short* A = (bx < 2) ? Xq : X;

  f32x4 acc[4][4];
  #pragma unroll
  for (int i = 0; i < 4; ++i)
    #pragma unroll
    for (int j = 0; j < 4; ++j) acc[i][j] = (f32x4){0.f, 0.f, 0.f, 0.f};

  for (int kt = 0; kt < 256; kt += 32) {
    __syncthreads();
    #pragma unroll
    for (int it = 0; it < 2; ++it) {
      int ch = tid + it * 256;
      int row = ch >> 2, seg = ch & 3;
      *(bf16x8*)&Al[row][seg * 8] = *(const bf16x8*)(A  + (size_t)(n0 + row) * 256 + kt + seg * 8);
      *(bf16x8*)&Wl[row][seg * 8] = *(const bf16x8*)(WT + (size_t)(c0 + row) * 256 + kt + seg * 8);
    }
    __syncthreads();
    bf16x8 wf[4], xf[4];
    #pragma unroll
    for (int ci = 0; ci < 4; ++ci) wf[ci] = *(bf16x8*)&Wl[cq * 64 + ci * 16 + lr][lg * 8];
    #pragma unroll
    for (int ni = 0; ni < 4; ++ni) xf[ni] = *(bf16x8*)&Al[nq * 64 + ni * 16 + lr][lg * 8];
    if (bx < 4) {
      #pragma unroll
      for (int ci = 0; ci < 4; ++ci)
        #pragma unroll
        for (int ni = 0; ni < 4; ++ni)
          acc[ci][ni] = __builtin_amdgcn_mfma_f32_16x16x32_bf16(wf[ci], xf[ni], acc[ci][ni], 0, 0, 0);
    } else {
      #pragma unroll
      for (int ci = 0; ci < 4; ++ci)
        #pragma unroll
        for (int ni = 0; ni < 4; ++ni)
          acc[ci][ni] = __builtin_amdgcn_mfma_f32_16x16x32_bf16(xf[ni], wf[ci], acc[ci][ni], 0, 0, 0);
    }
  }

  if (bx < 4) {
    // swapped: D[c][n]
    short* dst = (bx < 2) ? qb : kb;
    const int cl0 = (bx & 1) * 128;
    #pragma unroll
    for (int ci = 0; ci < 4; ++ci)
      #pragma unroll
      for (int ni = 0; ni < 4; ++ni) {
        int c = cl0 + cq * 64 + ci * 16 + lg * 4;
        int n = n0 + nq * 64 + ni * 16 + lr;
        *(short4v*)(dst + (size_t)n * 256 + c) = pack4(acc[ci][ni]);
      }
  } else {
    // normal: D[n][c] -> vT[c][n..n+3]
    const int cv0 = (bx - 4) * 128;
    #pragma unroll
    for (int ci = 0; ci < 4; ++ci)
      #pragma unroll
      for (int ni = 0; ni < 4; ++ni) {
        int c = cv0 + cq * 64 + ci * 16 + lr;
        int n = n0 + nq * 64 + ni * 16 + lg * 4;
        *(short4v*)(vTb + (size_t)c * NTOK + n) = pack4(acc[ci][ni]);
      }
  }
}

// ---------------- MFMA flash attention ----------------
// Key-tile loop is 64-ALIGNED so every staging load is 16B-aligned.
__global__ __launch_bounds__(256) void attn2(
    const short* __restrict__ qb, const short* __restrict__ kbuf,
    const short* __restrict__ vT, const int* __restrict__ cu,
    short* __restrict__ featb)
{
  __shared__ short Kl[64][40];
  __shared__ short Vt[32][72];
  __shared__ short Pl[64][72];
  const int h  = blockIdx.y;
  const int n0 = blockIdx.x * 64;
  const int tid = threadIdx.x;
  const int w = tid >> 6, l = tid & 63, lg = l >> 4, lr = l & 15;

  int cs[9];
  #pragma unroll
  for (int i = 0; i < 9; ++i) cs[i] = cu[i];

  int kbeg[4], kend[4];
  #pragma unroll
  for (int r = 0; r < 4; ++r) {
    int q = n0 + w * 16 + lg * 4 + r;
    int sg = 0;
    #pragma unroll
    for (int j = 1; j <= 8; ++j) sg += (cs[j] <= q);
    kbeg[r] = cs[sg]; kend[r] = cs[sg + 1];
  }
  int sg0 = 0, sgL = 0;
  #pragma unroll
  for (int j = 1; j <= 8; ++j) { sg0 += (cs[j] <= n0); sgL += (cs[j] <= n0 + 63); }
  const int lo = cs[sg0] & ~63;   // 64-aligned start (extra keys are masked)
  const int hi = cs[sgL + 1];

  const bf16x8 qf = *(const bf16x8*)(qb + (size_t)(n0 + w * 16 + lr) * 256 + h * 32 + lg * 8);

  f32x4 acc0 = {0.f, 0.f, 0.f, 0.f}, acc1 = {0.f, 0.f, 0.f, 0.f};
  float Lp[4] = {0.f, 0.f, 0.f, 0.f};
  const f32x4 z4 = {0.f, 0.f, 0.f, 0.f};

  for (int tb = lo; tb < hi; tb += 64) {
    __syncthreads();
    {
      // stage K tile [64][32]: exactly 256 bf16x8 chunks, one per thread
      int row = tid >> 2, seg = tid & 3;
      *(bf16x8*)&Kl[row][seg * 8] = *(const bf16x8*)(kbuf + (size_t)(tb + row) * 256 + h * 32 + seg * 8);
    }
    {
      // stage Vt [32][64]: 32 d-rows x 8 chunks of 8 keys (tb 64-aligned -> aligned)
      int d = tid >> 3, oc = tid & 7;
      *(bf16x8*)&Vt[d][oc * 8] = *(const bf16x8*)(vT + (size_t)(h * 32 + d) * NTOK + tb + oc * 8);
    }
    __syncthreads();

    // QK^T: 4 MFMAs -> lane holds S[q=lg*4+r][key=kb4*16+lr]
    f32x4 s[4];
    #pragma unroll
    for (int kb4 = 0; kb4 < 4; ++kb4) {
      bf16x8 kf = *(bf16x8*)&Kl[kb4 * 16 + lr][lg * 8];
      s[kb4] = __builtin_amdgcn_mfma_f32_16x16x32_bf16(qf, kf, z4, 0, 0, 0);
    }
    // mask + exp + P write (fixed max)
    #pragma unroll
    for (int kb4 = 0; kb4 < 4; ++kb4) {
      int kg = tb + kb4 * 16 + lr;
      #pragma unroll
      for (int r = 0; r < 4; ++r) {
        bool ok = (kg >= kbeg[r]) & (kg < kend[r]);
        float p = ok ? __expf(s[kb4][r]) : 0.f;
        Lp[r] += p;
        Pl[w * 16 + lg * 4 + r][kb4 * 16 + lr] = f2b(p);
      }
    }
    __syncthreads();

    // PV: 2 key-chunks x 2 d-blocks
    #pragma unroll
    for (int kc = 0; kc < 2; ++kc) {
      bf16x8 pf = *(bf16x8*)&Pl[w * 16 + lr][kc * 32 + lg * 8];
      bf16x8 v0 = *(bf16x8*)&Vt[lr][kc * 32 + lg * 8];
      bf16x8 v1 = *(bf16x8*)&Vt[16 + lr][kc * 32 + lg * 8];
      acc0 = __builtin_amdgcn_mfma_f32_16x16x32_bf16(pf, v0, acc0, 0, 0, 0);
      acc1 = __builtin_amdgcn_mfma_f32_16x16x32_bf16(pf, v1, acc1, 0, 0, 0);
    }
  }

  // reduce L across the 16-lane group and write feat (bf16)
  #pragma unroll
  for (int r = 0; r < 4; ++r) {
    float v = Lp[r];
    v += __shfl_xor(v, 1); v += __shfl_xor(v, 2);
    v += __shfl_xor(v, 4); v += __shfl_xor(v, 8);
    Lp[r] = 1.f / v;
  }
  #pragma unroll
  for (int r = 0; r < 4; ++r) {
    int n = n0 + w * 16 + lg * 4 + r;
    featb[(size_t)n * 256 + h * 32 + lr]      = f2b(acc0[r] * Lp[r]);
    featb[(size_t)n * 256 + h * 32 + 16 + lr] = f2b(acc1[r] * Lp[r]);
  }
}

// ---------------- output projection (MFMA, swapped orient) + bias ----------------
__global__ __launch_bounds__(256) void gemm_out(
    const short* __restrict__ Fb, const short* __restrict__ WpT,
    const float* __restrict__ bias, float* __restrict__ out)
{
  __shared__ short Al[128][40];
  __shared__ short Wl[128][40];
  const int c0 = blockIdx.x * 128;
  const int n0 = blockIdx.y * 128;
  const int tid = threadIdx.x;
  const int w = tid >> 6, l = tid & 63, lg = l >> 4, lr = l & 15;
  const int cq = w >> 1, nq = w & 1;

  f32x4 acc[4][4];
  #pragma unroll
  for (int i = 0; i < 4; ++i)
    #pragma unroll
    for (int j = 0; j < 4; ++j) acc[i][j] = (f32x4){0.f, 0.f, 0.f, 0.f};

  for (int kt = 0; kt < 256; kt += 32) {
    __syncthreads();
    #pragma unroll
    for (int it = 0; it < 2; ++it) {
      int ch = tid + it * 256;
      int row = ch >> 2, seg = ch & 3;
      *(bf16x8*)&Al[row][seg * 8] = *(const bf16x8*)(Fb  + (size_t)(n0 + row) * 256 + kt + seg * 8);
      *(bf16x8*)&Wl[row][seg * 8] = *(const bf16x8*)(WpT + (size_t)(c0 + row) * 256 + kt + seg * 8);
    }
    __syncthreads();
    bf16x8 wf[4], xf[4];
    #pragma unroll
    for (int ci = 0; ci < 4; ++ci) wf[ci] = *(bf16x8*)&Wl[cq * 64 + ci * 16 + lr][lg * 8];
    #pragma unroll
    for (int ni = 0; ni < 4; ++ni) xf[ni] = *(bf16x8*)&Al[nq * 64 + ni * 16 + lr][lg * 8];
    #pragma unroll
    for (int ci = 0; ci < 4; ++ci)
      #pragma unroll
      for (int ni = 0; ni < 4; ++ni)
        acc[ci][ni] = __builtin_amdgcn_mfma_f32_16x16x32_bf16(wf[ci], xf[ni], acc[ci][ni], 0, 0, 0);
  }

  #pragma unroll
  for (int ci = 0; ci < 4; ++ci)
    #pragma unroll
    for (int ni = 0; ni < 4; ++ni) {
      int c = c0 + cq * 64 + ci * 16 + lg * 4;
      int n = n0 + nq * 64 + ni * 16 + lr;
      f32x4 bv = *(const f32x4*)(bias + c);
      f32x4 o = acc[ci][ni] + bv;
      *(f32x4*)(out + (size_t)n * 256 + c) = o;
    }
}

extern "C" void kernel_launch(void* const* d_in, const int* in_sizes, int n_in,
                              void* d_out, int out_size, void* d_ws, size_t ws_size,
                              hipStream_t stream) {
  (void)in_sizes; (void)n_in; (void)out_size; (void)ws_size;
  const float* qkv   = (const float*)d_in[0];
  const float* q_pos = (const float*)d_in[1];
  const int*   cu    = (const int*)d_in[2];
  const float* Wq    = (const float*)d_in[4];
  const float* Wkv   = (const float*)d_in[5];
  const float* Wproj = (const float*)d_in[6];
  const float* bproj = (const float*)d_in[7];
  float* out = (float*)d_out;

  const size_t M = (size_t)NTOK * CDIM;   // 1048576
  short* S    = (short*)d_ws;
  short* Xq   = S;
  short* X    = S + M;
  short* qb   = S + 2 * M;
  short* kb   = S + 3 * M;
  short* vTb  = S + 4 * M;
  short* Fb   = S + 5 * M;
  short* WT   = S + 6 * M;
  short* WpT  = WT + 768 * 256;

  prep_kernel<<<1280, 256, 0, stream>>>(qkv, q_pos, Wq, Wkv, Wproj, Xq, X, WT, WpT);
  gemm_qkv<<<dim3(6, 32), 256, 0, stream>>>(Xq, X, WT, qb, kb, vTb);
  attn2<<<dim3(NTOK / 64, NH), 256, 0, stream>>>(qb, kb, vTb, cu, Fb);
  gemm_out<<<dim3(2, 32), 256, 0, stream>>>(Fb, WpT, bproj, out);
}

// Round 5
// 61.004 us; speedup vs baseline: 5.0682x; 1.2432x over previous
//
#include <hip/hip_runtime.h>
#include <hip/hip_bf16.h>
#include <math.h>

#define NTOK 4096
#define CDIM 256
#define NH   8
#define HD   32
#define SCALE 0.17677669529663687f  // 32^-0.5

typedef __attribute__((ext_vector_type(8))) short bf16x8;
typedef __attribute__((ext_vector_type(4))) short short4v;
typedef __attribute__((ext_vector_type(4))) float f32x4;

__device__ inline short f2b(float f) {
  union { __hip_bfloat16 h; short s; } u;
  u.h = __float2bfloat16(f);
  return u.s;
}
__device__ inline short4v pack4(f32x4 v) {
  short4v o; o[0] = f2b(v[0]); o[1] = f2b(v[1]); o[2] = f2b(v[2]); o[3] = f2b(v[3]);
  return o;
}

// ---------------- prep: bf16 conversions + weight transposes ----------------
__global__ __launch_bounds__(256) void prep_kernel(
    const float* __restrict__ qkv, const float* __restrict__ qpos,
    const float* __restrict__ Wq, const float* __restrict__ Wkv,
    const float* __restrict__ Wp,
    short* __restrict__ Xq, short* __restrict__ X,
    short* __restrict__ WT, short* __restrict__ WpT)
{
  const int b = blockIdx.x, t = threadIdx.x;
  if (b < 1024) {
    const int i4 = (b * 256 + t) * 4;
    float4 a = *(const float4*)(qkv + i4);
    float4 p = *(const float4*)(qpos + i4);
    short4v xo, qo;
    xo[0] = f2b(a.x); xo[1] = f2b(a.y); xo[2] = f2b(a.z); xo[3] = f2b(a.w);
    qo[0] = f2b(a.x + p.x); qo[1] = f2b(a.y + p.y); qo[2] = f2b(a.z + p.z); qo[3] = f2b(a.w + p.w);
    *(short4v*)(X + i4)  = xo;
    *(short4v*)(Xq + i4) = qo;
  } else {
    const int gid = (b - 1024) * 256 + t;   // 0..65535
    const int c  = gid & 1023;              // output row (transposed col)
    const int k4 = (gid >> 10) * 4;         // 0..252
    short4v o;
    if (c < 768) {
      #pragma unroll
      for (int j = 0; j < 4; ++j) {
        int k = k4 + j;
        float v = (c < 256) ? Wq[(size_t)k * 256 + c] * SCALE
                            : Wkv[(size_t)k * 512 + (c - 256)];
        o[j] = f2b(v);
      }
      *(short4v*)(WT + (size_t)c * 256 + k4) = o;
    } else {
      const int cc = c - 768;
      #pragma unroll
      for (int j = 0; j < 4; ++j) o[j] = f2b(Wp[(size_t)(k4 + j) * 256 + cc]);
      *(short4v*)(WpT + (size_t)cc * 256 + k4) = o;
    }
  }
}

// ---------------- fused QKV projection (MFMA, 64x64 tiles) ----------------
// bx 0..3: q (Xq, swapped -> qb[n][c]); bx 4..7: k (X, swapped -> kb[n][c]);
// bx 8..11: v (X, normal -> vT[c][n])
__global__ __launch_bounds__(256) void gemm_qkv(
    const short* __restrict__ Xq, const short* __restrict__ X,
    const short* __restrict__ WT,
    short* __restrict__ qb, short* __restrict__ kb, short* __restrict__ vTb)
{
  __shared__ short Al[64][40];
  __shared__ short Wl[64][40];
  const int bx = blockIdx.x;
  const int n0 = blockIdx.y * 64;
  const int c0 = bx * 64;                   // row range in WT [0,768)
  const int tid = threadIdx.x;
  const int w = tid >> 6, l = tid & 63, lg = l >> 4, lr = l & 15;
  const int wc = w & 1, wn = w >> 1;        // 32-col half, 32-row half
  const short* A = (bx < 4) ? Xq : X;

  f32x4 acc[2][2];
  #pragma unroll
  for (int i = 0; i < 2; ++i)
    #pragma unroll
    for (int j = 0; j < 2; ++j) acc[i][j] = (f32x4){0.f, 0.f, 0.f, 0.f};

  for (int kt = 0; kt < 256; kt += 32) {
    __syncthreads();
    {
      int row = tid >> 2, seg = tid & 3;    // 64 rows x 4 chunks of 8
      *(bf16x8*)&Al[row][seg * 8] = *(const bf16x8*)(A  + (size_t)(n0 + row) * 256 + kt + seg * 8);
      *(bf16x8*)&Wl[row][seg * 8] = *(const bf16x8*)(WT + (size_t)(c0 + row) * 256 + kt + seg * 8);
    }
    __syncthreads();
    bf16x8 wf[2], xf[2];
    #pragma unroll
    for (int ci = 0; ci < 2; ++ci) wf[ci] = *(bf16x8*)&Wl[wc * 32 + ci * 16 + lr][lg * 8];
    #pragma unroll
    for (int ni = 0; ni < 2; ++ni) xf[ni] = *(bf16x8*)&Al[wn * 32 + ni * 16 + lr][lg * 8];
    if (bx < 8) {
      #pragma unroll
      for (int ci = 0; ci < 2; ++ci)
        #pragma unroll
        for (int ni = 0; ni < 2; ++ni)
          acc[ci][ni] = __builtin_amdgcn_mfma_f32_16x16x32_bf16(wf[ci], xf[ni], acc[ci][ni], 0, 0, 0);
    } else {
      #pragma unroll
      for (int ci = 0; ci < 2; ++ci)
        #pragma unroll
        for (int ni = 0; ni < 2; ++ni)
          acc[ci][ni] = __builtin_amdgcn_mfma_f32_16x16x32_bf16(xf[ni], wf[ci], acc[ci][ni], 0, 0, 0);
    }
  }

  if (bx < 8) {
    // swapped: D[c][n]; lane holds 4 consecutive c, one n
    short* dst = (bx < 4) ? qb : kb;
    const int cl0 = (bx & 3) * 64;
    #pragma unroll
    for (int ci = 0; ci < 2; ++ci)
      #pragma unroll
      for (int ni = 0; ni < 2; ++ni) {
        int c = cl0 + wc * 32 + ci * 16 + lg * 4;
        int n = n0 + wn * 32 + ni * 16 + lr;
        *(short4v*)(dst + (size_t)n * 256 + c) = pack4(acc[ci][ni]);
      }
  } else {
    // normal: D[n][c]; lane holds 4 consecutive n, one c -> vT[c][n..n+3]
    const int cv0 = (bx - 8) * 64;
    #pragma unroll
    for (int ci = 0; ci < 2; ++ci)
      #pragma unroll
      for (int ni = 0; ni < 2; ++ni) {
        int c = cv0 + wc * 32 + ci * 16 + lr;
        int n = n0 + wn * 32 + ni * 16 + lg * 4;
        *(short4v*)(vTb + (size_t)c * NTOK + n) = pack4(acc[ci][ni]);
      }
  }
}

// ---------------- wave-independent MFMA flash attention ----------------
// wave = (16 queries, 1 head); no __syncthreads; K/V direct from global
// (L2-resident) with register double-buffer; P transposed via per-wave LDS.
__global__ __launch_bounds__(256) void attn3(
    const short* __restrict__ qb, const short* __restrict__ kbuf,
    const short* __restrict__ vT, const int* __restrict__ cu,
    short* __restrict__ featb)
{
  __shared__ short Pl[4][16][44];           // per-wave P scratch, 44-pad
  const int tid = threadIdx.x;
  const int w = tid >> 6, l = tid & 63, lg = l >> 4, lr = l & 15;
  const int gw = blockIdx.x * 4 + w;        // 0..2047
  const int h = gw & 7, t = gw >> 3;        // same t across block's 4 waves
  const int n0 = t * 16;

  int cs[9];
  #pragma unroll
  for (int i = 0; i < 9; ++i) cs[i] = cu[i];

  int kbeg[4], kend[4];
  #pragma unroll
  for (int r = 0; r < 4; ++r) {
    int q = n0 + lg * 4 + r;
    int sg = 0;
    #pragma unroll
    for (int j = 1; j <= 8; ++j) sg += (cs[j] <= q);
    kbeg[r] = cs[sg]; kend[r] = cs[sg + 1];
  }
  int sg0 = 0, sgL = 0;
  #pragma unroll
  for (int j = 1; j <= 8; ++j) { sg0 += (cs[j] <= n0); sgL += (cs[j] <= n0 + 15); }
  const int lo = cs[sg0] & ~31;             // 32-aligned (extra keys masked)
  const int hi = cs[sgL + 1];

  const bf16x8 qf = *(const bf16x8*)(qb + (size_t)(n0 + lr) * 256 + h * 32 + lg * 8);
  const short* kB = kbuf + h * 32 + lg * 8;
  const short* vA = vT + (size_t)(h * 32 + lr) * NTOK + lg * 8;
  const short* vB = vT + (size_t)(h * 32 + 16 + lr) * NTOK + lg * 8;

  f32x4 acc0 = {0.f, 0.f, 0.f, 0.f}, acc1 = {0.f, 0.f, 0.f, 0.f};
  float Lp[4] = {0.f, 0.f, 0.f, 0.f};
  const f32x4 z4 = {0.f, 0.f, 0.f, 0.f};

  int tb = lo;
  bf16x8 ka = *(const bf16x8*)(kB + (size_t)(tb + lr) * 256);
  bf16x8 kc = *(const bf16x8*)(kB + (size_t)(tb + 16 + lr) * 256);
  bf16x8 va = *(const bf16x8*)(vA + tb);
  bf16x8 vb = *(const bf16x8*)(vB + tb);

  for (; tb < hi; tb += 32) {
    const int tn = (tb + 32 < hi) ? (tb + 32) : tb;   // prefetch (clamped)
    bf16x8 kna = *(const bf16x8*)(kB + (size_t)(tn + lr) * 256);
    bf16x8 knc = *(const bf16x8*)(kB + (size_t)(tn + 16 + lr) * 256);
    bf16x8 vna = *(const bf16x8*)(vA + tn);
    bf16x8 vnb = *(const bf16x8*)(vB + tn);

    f32x4 s0 = __builtin_amdgcn_mfma_f32_16x16x32_bf16(qf, ka, z4, 0, 0, 0);
    f32x4 s1 = __builtin_amdgcn_mfma_f32_16x16x32_bf16(qf, kc, z4, 0, 0, 0);

    // mask + exp + P transpose through per-wave LDS (no barrier: in-wave only)
    #pragma unroll
    for (int r = 0; r < 4; ++r) {
      int kg0 = tb + lr;
      bool ok0 = (kg0 >= kbeg[r]) & (kg0 < kend[r]);
      float p0 = ok0 ? __expf(s0[r]) : 0.f;
      int kg1 = tb + 16 + lr;
      bool ok1 = (kg1 >= kbeg[r]) & (kg1 < kend[r]);
      float p1 = ok1 ? __expf(s1[r]) : 0.f;
      Lp[r] += p0 + p1;
      Pl[w][lg * 4 + r][lr]      = f2b(p0);
      Pl[w][lg * 4 + r][16 + lr] = f2b(p1);
    }
    bf16x8 pf = *(bf16x8*)&Pl[w][lr][lg * 8];

    acc0 = __builtin_amdgcn_mfma_f32_16x16x32_bf16(pf, va, acc0, 0, 0, 0);
    acc1 = __builtin_amdgcn_mfma_f32_16x16x32_bf16(pf, vb, acc1, 0, 0, 0);

    ka = kna; kc = knc; va = vna; vb = vnb;
  }

  // L-sum across the 16-lane group, then write feat (bf16)
  #pragma unroll
  for (int r = 0; r < 4; ++r) {
    float v = Lp[r];
    v += __shfl_xor(v, 1); v += __shfl_xor(v, 2);
    v += __shfl_xor(v, 4); v += __shfl_xor(v, 8);
    Lp[r] = 1.f / v;
  }
  #pragma unroll
  for (int r = 0; r < 4; ++r) {
    int n = n0 + lg * 4 + r;
    featb[(size_t)n * 256 + h * 32 + lr]      = f2b(acc0[r] * Lp[r]);
    featb[(size_t)n * 256 + h * 32 + 16 + lr] = f2b(acc1[r] * Lp[r]);
  }
}

// ---------------- output projection (MFMA, 64x64 tiles, swapped) + bias ----------------
__global__ __launch_bounds__(256) void gemm_out(
    const short* __restrict__ Fb, const short* __restrict__ WpT,
    const float* __restrict__ bias, float* __restrict__ out)
{
  __shared__ short Al[64][40];
  __shared__ short Wl[64][40];
  const int c0 = blockIdx.x * 64;
  const int n0 = blockIdx.y * 64;
  const int tid = threadIdx.x;
  const int w = tid >> 6, l = tid & 63, lg = l >> 4, lr = l & 15;
  const int wc = w & 1, wn = w >> 1;

  f32x4 acc[2][2];
  #pragma unroll
  for (int i = 0; i < 2; ++i)
    #pragma unroll
    for (int j = 0; j < 2; ++j) acc[i][j] = (f32x4){0.f, 0.f, 0.f, 0.f};

  for (int kt = 0; kt < 256; kt += 32) {
    __syncthreads();
    {
      int row = tid >> 2, seg = tid & 3;
      *(bf16x8*)&Al[row][seg * 8] = *(const bf16x8*)(Fb  + (size_t)(n0 + row) * 256 + kt + seg * 8);
      *(bf16x8*)&Wl[row][seg * 8] = *(const bf16x8*)(WpT + (size_t)(c0 + row) * 256 + kt + seg * 8);
    }
    __syncthreads();
    bf16x8 wf[2], xf[2];
    #pragma unroll
    for (int ci = 0; ci < 2; ++ci) wf[ci] = *(bf16x8*)&Wl[wc * 32 + ci * 16 + lr][lg * 8];
    #pragma unroll
    for (int ni = 0; ni < 2; ++ni) xf[ni] = *(bf16x8*)&Al[wn * 32 + ni * 16 + lr][lg * 8];
    #pragma unroll
    for (int ci = 0; ci < 2; ++ci)
      #pragma unroll
      for (int ni = 0; ni < 2; ++ni)
        acc[ci][ni] = __builtin_amdgcn_mfma_f32_16x16x32_bf16(wf[ci], xf[ni], acc[ci][ni], 0, 0, 0);
  }

  #pragma unroll
  for (int ci = 0; ci < 2; ++ci)
    #pragma unroll
    for (int ni = 0; ni < 2; ++ni) {
      int c = c0 + wc * 32 + ci * 16 + lg * 4;
      int n = n0 + wn * 32 + ni * 16 + lr;
      f32x4 bv = *(const f32x4*)(bias + c);
      f32x4 o = acc[ci][ni] + bv;
      *(f32x4*)(out + (size_t)n * 256 + c) = o;
    }
}

extern "C" void kernel_launch(void* const* d_in, const int* in_sizes, int n_in,
                              void* d_out, int out_size, void* d_ws, size_t ws_size,
                              hipStream_t stream) {
  (void)in_sizes; (void)n_in; (void)out_size; (void)ws_size;
  const float* qkv   = (const float*)d_in[0];
  const float* q_pos = (const float*)d_in[1];
  const int*   cu    = (const int*)d_in[2];
  const float* Wq    = (const float*)d_in[4];
  const float* Wkv   = (const float*)d_in[5];
  const float* Wproj = (const float*)d_in[6];
  const float* bproj = (const float*)d_in[7];
  float* out = (float*)d_out;

  const size_t M = (size_t)NTOK * CDIM;   // 1048576
  short* S    = (short*)d_ws;
  short* Xq   = S;
  short* X    = S + M;
  short* qb   = S + 2 * M;
  short* kb   = S + 3 * M;
  short* vTb  = S + 4 * M;
  short* Fb   = S + 5 * M;
  short* WT   = S + 6 * M;
  short* WpT  = WT + 768 * 256;

  prep_kernel<<<1280, 256, 0, stream>>>(qkv, q_pos, Wq, Wkv, Wproj, Xq, X, WT, WpT);
  gemm_qkv<<<dim3(12, 64), 256, 0, stream>>>(Xq, X, WT, qb, kb, vTb);
  attn3<<<512, 256, 0, stream>>>(qb, kb, vTb, cu, Fb);
  gemm_out<<<dim3(4, 64), 256, 0, stream>>>(Fb, WpT, bproj, out);
}

// Round 6
// 55.054 us; speedup vs baseline: 5.6159x; 1.1081x over previous
//
#include <hip/hip_runtime.h>
#include <hip/hip_bf16.h>
#include <math.h>

#define NTOK 4096
#define CDIM 256
#define NH   8
#define HD   32
#define SCALE 0.17677669529663687f  // 32^-0.5

typedef __attribute__((ext_vector_type(8))) short bf16x8;
typedef __attribute__((ext_vector_type(4))) short short4v;
typedef __attribute__((ext_vector_type(4))) float f32x4;

__device__ inline short f2b(float f) {
  union { __hip_bfloat16 h; short s; } u;
  u.h = __float2bfloat16(f);
  return u.s;
}
__device__ inline short4v pack4(f32x4 v) {
  short4v o; o[0] = f2b(v[0]); o[1] = f2b(v[1]); o[2] = f2b(v[2]); o[3] = f2b(v[3]);
  return o;
}

// ---------------- prep: bf16 conversions + weight transposes ----------------
__global__ __launch_bounds__(256) void prep_kernel(
    const float* __restrict__ qkv, const float* __restrict__ qpos,
    const float* __restrict__ Wq, const float* __restrict__ Wkv,
    const float* __restrict__ Wp,
    short* __restrict__ Xq, short* __restrict__ X,
    short* __restrict__ WT, short* __restrict__ WpT)
{
  const int b = blockIdx.x, t = threadIdx.x;
  if (b < 1024) {
    const int i4 = (b * 256 + t) * 4;
    float4 a = *(const float4*)(qkv + i4);
    float4 p = *(const float4*)(qpos + i4);
    short4v xo, qo;
    xo[0] = f2b(a.x); xo[1] = f2b(a.y); xo[2] = f2b(a.z); xo[3] = f2b(a.w);
    qo[0] = f2b(a.x + p.x); qo[1] = f2b(a.y + p.y); qo[2] = f2b(a.z + p.z); qo[3] = f2b(a.w + p.w);
    *(short4v*)(X + i4)  = xo;
    *(short4v*)(Xq + i4) = qo;
  } else {
    const int gid = (b - 1024) * 256 + t;   // 0..65535
    const int c  = gid & 1023;              // output row (transposed col)
    const int k4 = (gid >> 10) * 4;         // 0..252
    short4v o;
    if (c < 768) {
      #pragma unroll
      for (int j = 0; j < 4; ++j) {
        int k = k4 + j;
        float v = (c < 256) ? Wq[(size_t)k * 256 + c] * SCALE
                            : Wkv[(size_t)k * 512 + (c - 256)];
        o[j] = f2b(v);
      }
      *(short4v*)(WT + (size_t)c * 256 + k4) = o;
    } else {
      const int cc = c - 768;
      #pragma unroll
      for (int j = 0; j < 4; ++j) o[j] = f2b(Wp[(size_t)(k4 + j) * 256 + cc]);
      *(short4v*)(WpT + (size_t)cc * 256 + k4) = o;
    }
  }
}

// ---------------- fused QKV projection (MFMA, 64x64 tiles) ----------------
__global__ __launch_bounds__(256) void gemm_qkv(
    const short* __restrict__ Xq, const short* __restrict__ X,
    const short* __restrict__ WT,
    short* __restrict__ qb, short* __restrict__ kb, short* __restrict__ vTb)
{
  __shared__ short Al[64][40];
  __shared__ short Wl[64][40];
  const int bx = blockIdx.x;
  const int n0 = blockIdx.y * 64;
  const int c0 = bx * 64;                   // row range in WT [0,768)
  const int tid = threadIdx.x;
  const int w = tid >> 6, l = tid & 63, lg = l >> 4, lr = l & 15;
  const int wc = w & 1, wn = w >> 1;
  const short* A = (bx < 4) ? Xq : X;

  f32x4 acc[2][2];
  #pragma unroll
  for (int i = 0; i < 2; ++i)
    #pragma unroll
    for (int j = 0; j < 2; ++j) acc[i][j] = (f32x4){0.f, 0.f, 0.f, 0.f};

  for (int kt = 0; kt < 256; kt += 32) {
    __syncthreads();
    {
      int row = tid >> 2, seg = tid & 3;
      *(bf16x8*)&Al[row][seg * 8] = *(const bf16x8*)(A  + (size_t)(n0 + row) * 256 + kt + seg * 8);
      *(bf16x8*)&Wl[row][seg * 8] = *(const bf16x8*)(WT + (size_t)(c0 + row) * 256 + kt + seg * 8);
    }
    __syncthreads();
    bf16x8 wf[2], xf[2];
    #pragma unroll
    for (int ci = 0; ci < 2; ++ci) wf[ci] = *(bf16x8*)&Wl[wc * 32 + ci * 16 + lr][lg * 8];
    #pragma unroll
    for (int ni = 0; ni < 2; ++ni) xf[ni] = *(bf16x8*)&Al[wn * 32 + ni * 16 + lr][lg * 8];
    if (bx < 8) {
      #pragma unroll
      for (int ci = 0; ci < 2; ++ci)
        #pragma unroll
        for (int ni = 0; ni < 2; ++ni)
          acc[ci][ni] = __builtin_amdgcn_mfma_f32_16x16x32_bf16(wf[ci], xf[ni], acc[ci][ni], 0, 0, 0);
    } else {
      #pragma unroll
      for (int ci = 0; ci < 2; ++ci)
        #pragma unroll
        for (int ni = 0; ni < 2; ++ni)
          acc[ci][ni] = __builtin_amdgcn_mfma_f32_16x16x32_bf16(xf[ni], wf[ci], acc[ci][ni], 0, 0, 0);
    }
  }

  if (bx < 8) {
    short* dst = (bx < 4) ? qb : kb;
    const int cl0 = (bx & 3) * 64;
    #pragma unroll
    for (int ci = 0; ci < 2; ++ci)
      #pragma unroll
      for (int ni = 0; ni < 2; ++ni) {
        int c = cl0 + wc * 32 + ci * 16 + lg * 4;
        int n = n0 + wn * 32 + ni * 16 + lr;
        *(short4v*)(dst + (size_t)n * 256 + c) = pack4(acc[ci][ni]);
      }
  } else {
    const int cv0 = (bx - 8) * 64;
    #pragma unroll
    for (int ci = 0; ci < 2; ++ci)
      #pragma unroll
      for (int ni = 0; ni < 2; ++ni) {
        int c = cv0 + wc * 32 + ci * 16 + lr;
        int n = n0 + wn * 32 + ni * 16 + lg * 4;
        *(short4v*)(vTb + (size_t)c * NTOK + n) = pack4(acc[ci][ni]);
      }
  }
}

// ---------------- attn4: LDS-free loop + 4-way key split ----------------
// block = (16-query tile, head); 4 waves each take a contiguous quarter of
// the key range. Swapped QK with permuted K rows puts P directly into the
// PV A-fragment layout (no LDS, no shuffles in the loop). Fixed-max softmax
// makes the split merge a pure sum (one LDS reduce at the end).
__global__ __launch_bounds__(256) void attn4(
    const short* __restrict__ qb, const short* __restrict__ kbuf,
    const short* __restrict__ vT, const int* __restrict__ cu,
    short* __restrict__ featb)
{
  __shared__ float red[4][64][9];
  const int tid = threadIdx.x;
  const int w = tid >> 6, l = tid & 63, lg = l >> 4, lr = l & 15;
  const int h = blockIdx.x & 7, t = blockIdx.x >> 3;   // 2048 blocks
  const int n0 = t * 16;

  int cs[9];
  #pragma unroll
  for (int i = 0; i < 9; ++i) cs[i] = cu[i];

  const int qn = n0 + lr;                   // this lane's query (for masking)
  int sg = 0, sg0 = 0, sgL = 0;
  #pragma unroll
  for (int j = 1; j <= 8; ++j) {
    sg  += (cs[j] <= qn);
    sg0 += (cs[j] <= n0);
    sgL += (cs[j] <= n0 + 15);
  }
  const int kbegL = cs[sg], kendL = cs[sg + 1];
  const int lo = cs[sg0] & ~31;             // 32-aligned union start
  const int hi = cs[sgL + 1];
  const int nT = (hi - lo + 31) >> 5;       // 32-key tiles
  const int qT = (nT + 3) >> 2;
  const int it0 = w * qT;
  const int it1 = (it0 + qT < nT) ? (it0 + qT) : nT;

  const bf16x8 qf = *(const bf16x8*)(qb + (size_t)qn * 256 + h * 32 + lg * 8);
  const int kperm = (lr >> 2) * 8 + (lr & 3);           // row lr <-> key 8a+r
  const short* kP  = kbuf + h * 32 + lg * 8;            // + key*256
  const short* vP0 = vT + (size_t)(h * 32 + lr) * NTOK;       // d = lr
  const short* vP1 = vT + (size_t)(h * 32 + 16 + lr) * NTOK;  // d = 16+lr

  f32x4 acc0 = {0.f, 0.f, 0.f, 0.f}, acc1 = {0.f, 0.f, 0.f, 0.f};
  float Lp = 0.f;
  const f32x4 z4 = {0.f, 0.f, 0.f, 0.f};

  if (it0 < it1) {
    int tb = lo + it0 * 32;
    bf16x8 ka = *(const bf16x8*)(kP + (size_t)(tb + kperm) * 256);
    bf16x8 kc = *(const bf16x8*)(kP + (size_t)(tb + kperm + 4) * 256);
    bf16x8 va = *(const bf16x8*)(vP0 + tb + lg * 8);
    bf16x8 vb = *(const bf16x8*)(vP1 + tb + lg * 8);
    for (int it = it0; it < it1; ++it) {
      const int tn = lo + ((it + 1 < it1) ? (it + 1) : it) * 32;
      bf16x8 kna = *(const bf16x8*)(kP + (size_t)(tn + kperm) * 256);
      bf16x8 knc = *(const bf16x8*)(kP + (size_t)(tn + kperm + 4) * 256);
      bf16x8 vna = *(const bf16x8*)(vP0 + tn + lg * 8);
      bf16x8 vnb = *(const bf16x8*)(vP1 + tn + lg * 8);

      // swapped QK: s0[r] = S[key=tb+lg*8+r][q=lr], s1[r] = +4
      f32x4 s0 = __builtin_amdgcn_mfma_f32_16x16x32_bf16(ka, qf, z4, 0, 0, 0);
      f32x4 s1 = __builtin_amdgcn_mfma_f32_16x16x32_bf16(kc, qf, z4, 0, 0, 0);

      const int kgb = tb + lg * 8;
      bf16x8 pf;
      #pragma unroll
      for (int r = 0; r < 4; ++r) {
        int k0 = kgb + r;
        bool ok0 = (k0 >= kbegL) & (k0 < kendL);
        float p0 = ok0 ? __expf(s0[r]) : 0.f;
        int k1 = kgb + 4 + r;
        bool ok1 = (k1 >= kbegL) & (k1 < kendL);
        float p1 = ok1 ? __expf(s1[r]) : 0.f;
        Lp += p0 + p1;
        pf[r]     = f2b(p0);
        pf[4 + r] = f2b(p1);
      }
      // PV: lane's pf is P[q=lr][keys kgb..kgb+7] = exact A-fragment
      acc0 = __builtin_amdgcn_mfma_f32_16x16x32_bf16(pf, va, acc0, 0, 0, 0);
      acc1 = __builtin_amdgcn_mfma_f32_16x16x32_bf16(pf, vb, acc1, 0, 0, 0);

      ka = kna; kc = knc; va = vna; vb = vnb;
      tb = tn;
    }
  }

  // merge the 4 key-splits: pure sum (fixed-max softmax)
  #pragma unroll
  for (int r = 0; r < 4; ++r) { red[w][l][r] = acc0[r]; red[w][l][4 + r] = acc1[r]; }
  red[w][l][8] = Lp;
  __syncthreads();
  if (w == 0) {
    float a0[4] = {0.f, 0.f, 0.f, 0.f}, a1[4] = {0.f, 0.f, 0.f, 0.f}, Ls = 0.f;
    #pragma unroll
    for (int wv = 0; wv < 4; ++wv) {
      #pragma unroll
      for (int r = 0; r < 4; ++r) { a0[r] += red[wv][l][r]; a1[r] += red[wv][l][4 + r]; }
      Ls += red[wv][l][8];
    }
    // L lives at q=lr, spread over the 4 lg groups: butterfly then invert
    Ls += __shfl_xor(Ls, 16);
    Ls += __shfl_xor(Ls, 32);
    float inv = 1.f / Ls;                    // valid for q = n0 + lr
    #pragma unroll
    for (int r = 0; r < 4; ++r) {
      float iq = __shfl(inv, lg * 4 + r);    // lane lg*4+r (<16) has q=lg*4+r
      int n = n0 + lg * 4 + r;
      featb[(size_t)n * 256 + h * 32 + lr]      = f2b(a0[r] * iq);
      featb[(size_t)n * 256 + h * 32 + 16 + lr] = f2b(a1[r] * iq);
    }
  }
}

// ---------------- output projection (MFMA, 64x64 tiles, swapped) + bias ----------------
__global__ __launch_bounds__(256) void gemm_out(
    const short* __restrict__ Fb, const short* __restrict__ WpT,
    const float* __restrict__ bias, float* __restrict__ out)
{
  __shared__ short Al[64][40];
  __shared__ short Wl[64][40];
  const int c0 = blockIdx.x * 64;
  const int n0 = blockIdx.y * 64;
  const int tid = threadIdx.x;
  const int w = tid >> 6, l = tid & 63, lg = l >> 4, lr = l & 15;
  const int wc = w & 1, wn = w >> 1;

  f32x4 acc[2][2];
  #pragma unroll
  for (int i = 0; i < 2; ++i)
    #pragma unroll
    for (int j = 0; j < 2; ++j) acc[i][j] = (f32x4){0.f, 0.f, 0.f, 0.f};

  for (int kt = 0; kt < 256; kt += 32) {
    __syncthreads();
    {
      int row = tid >> 2, seg = tid & 3;
      *(bf16x8*)&Al[row][seg * 8] = *(const bf16x8*)(Fb  + (size_t)(n0 + row) * 256 + kt + seg * 8);
      *(bf16x8*)&Wl[row][seg * 8] = *(const bf16x8*)(WpT + (size_t)(c0 + row) * 256 + kt + seg * 8);
    }
    __syncthreads();
    bf16x8 wf[2], xf[2];
    #pragma unroll
    for (int ci = 0; ci < 2; ++ci) wf[ci] = *(bf16x8*)&Wl[wc * 32 + ci * 16 + lr][lg * 8];
    #pragma unroll
    for (int ni = 0; ni < 2; ++ni) xf[ni] = *(bf16x8*)&Al[wn * 32 + ni * 16 + lr][lg * 8];
    #pragma unroll
    for (int ci = 0; ci < 2; ++ci)
      #pragma unroll
      for (int ni = 0; ni < 2; ++ni)
        acc[ci][ni] = __builtin_amdgcn_mfma_f32_16x16x32_bf16(wf[ci], xf[ni], acc[ci][ni], 0, 0, 0);
  }

  #pragma unroll
  for (int ci = 0; ci < 2; ++ci)
    #pragma unroll
    for (int ni = 0; ni < 2; ++ni) {
      int c = c0 + wc * 32 + ci * 16 + lg * 4;
      int n = n0 + wn * 32 + ni * 16 + lr;
      f32x4 bv = *(const f32x4*)(bias + c);
      f32x4 o = acc[ci][ni] + bv;
      *(f32x4*)(out + (size_t)n * 256 + c) = o;
    }
}

extern "C" void kernel_launch(void* const* d_in, const int* in_sizes, int n_in,
                              void* d_out, int out_size, void* d_ws, size_t ws_size,
                              hipStream_t stream) {
  (void)in_sizes; (void)n_in; (void)out_size; (void)ws_size;
  const float* qkv   = (const float*)d_in[0];
  const float* q_pos = (const float*)d_in[1];
  const int*   cu    = (const int*)d_in[2];
  const float* Wq    = (const float*)d_in[4];
  const float* Wkv   = (const float*)d_in[5];
  const float* Wproj = (const float*)d_in[6];
  const float* bproj = (const float*)d_in[7];
  float* out = (float*)d_out;

  const size_t M = (size_t)NTOK * CDIM;   // 1048576
  short* S    = (short*)d_ws;
  short* Xq   = S;
  short* X    = S + M;
  short* qb   = S + 2 * M;
  short* kb   = S + 3 * M;
  short* vTb  = S + 4 * M;
  short* Fb   = S + 5 * M;
  short* WT   = S + 6 * M;
  short* WpT  = WT + 768 * 256;

  prep_kernel<<<1280, 256, 0, stream>>>(qkv, q_pos, Wq, Wkv, Wproj, Xq, X, WT, WpT);
  gemm_qkv<<<dim3(12, 64), 256, 0, stream>>>(Xq, X, WT, qb, kb, vTb);
  attn4<<<2048, 256, 0, stream>>>(qb, kb, vTb, cu, Fb);
  gemm_out<<<dim3(4, 64), 256, 0, stream>>>(Fb, WpT, bproj, out);
}